// Round 11
// baseline (236.277 us; speedup 1.0000x reference)
//
#include <hip/hip_runtime.h>
#include <math.h>

#define BATCH 8
#define CH    256
#define H     128
#define W     128
#define HW    (H * W)          // 16384
#define OH    65
#define OW    65
#define NPIX  (OH * OW)        // 4225

// ---------------- K1: channel L2 norms, pure stream (verified) ----------------
// 512 blocks (2/CU) x 256 thr (4 waves). Block = 256-pixel tile of one image;
// wave wv covers channels [wv*64, wv*64+64). Per channel the wave reads
// 1 KB contiguous; 64 independent loads/lane -> deep pipeline. Primes L3 with x.
__global__ __launch_bounds__(256) void norm_kernel(const float4* __restrict__ x4,
                                                   float* __restrict__ nrm) {
    const int b    = blockIdx.x >> 6;      // 0..7
    const int t    = blockIdx.x & 63;      // 256-px tile within image
    const int lane = threadIdx.x & 63;
    const int wv   = threadIdx.x >> 6;     // 0..3

    const float4* p = x4 + (size_t)(b * CH + wv * 64) * (HW / 4) + t * 64 + lane;
    float4 a = {0.f, 0.f, 0.f, 0.f};
    #pragma unroll 8
    for (int c = 0; c < 64; ++c) {
        float4 v = p[(size_t)c * (HW / 4)];
        a.x += v.x * v.x; a.y += v.y * v.y;
        a.z += v.z * v.z; a.w += v.w * v.w;
    }
    __shared__ float part[4][256];
    ((float4*)part[wv])[lane] = a;         // flat px index = 4*lane+comp
    __syncthreads();
    float s = part[0][threadIdx.x] + part[1][threadIdx.x]
            + part[2][threadIdx.x] + part[3][threadIdx.x];
    nrm[(size_t)b * HW + t * 256 + threadIdx.x] = sqrtf(s);
}

// ---------------- K2: rolling-row sequential pool, in-lane softmax ----------
// 512 blocks (2/CU) x 256 thr; wave = one channel plane (c = (bid>>3)*4 + wv).
// Rolling rows: oh needs input rows (2oh-2, 2oh-1, 2oh); row 2oh-2 is the
// previous iteration's row 2oh (register copy), so exactly 2 NEW x rows and
// 2 NEW norm rows load per step, ascending addresses -> each 64 KB plane is
// read once, sequentially (K1-like stream). Norm slice/image = 64 KB, L2-hot.
//
// Lane l holds cols (2l, 2l+1) of x and norm rows. It computes the FULL
// softmax set for ow = l+1 (window cols 2l, 2l+1, 2l+2; the third col's norm
// and x come via one shfl_down per row) and writes the complete out[oh][l+1].
// Lane 0 additionally computes out[oh][0] (set[0]: only col 0 in-bounds).
// Masking replicates the verified math: OOB -> nv=0 in denom (m seeded 0),
// weight=0 in numerator. Rows -2/-1 (oh=0) and 128 (oh=64) are masked the
// same way, so the dummy rolled registers are harmless.
__global__ __launch_bounds__(256) void pool_kernel(const float* __restrict__ x,
                                                   const float* __restrict__ nrm,
                                                   float* __restrict__ out) {
    const int b    = blockIdx.x & 7;       // XCD pin: image -> XCD
    const int g    = blockIdx.x >> 3;      // 0..63 channel group
    const int lane = threadIdx.x & 63;
    const int wv   = threadIdx.x >> 6;     // 0..3
    const int c    = g * 4 + wv;

    const float2* xr = (const float2*)(x + (size_t)(b * CH + c) * HW);
    const float2* nr = (const float2*)(nrm + (size_t)b * HW);
    float*        op = out + (size_t)(b * CH + c) * NPIX;

    float2 xv2 = xr[lane], nv2 = nr[lane];          // row 0
    float2 xv0 = xv2, xv1 = xv2;                    // rows -2,-1: dummies,
    float2 nv0 = nv2, nv1 = nv2;                    // masked to weight 0

    #pragma unroll 4
    for (int oh = 0; oh < OH; ++oh) {
        if (oh > 0) {
            xv0 = xv2; nv0 = nv2;                   // row 2oh-2
            const int r1 = 2 * oh - 1;              // always in [1,127]
            const int r2 = (2 * oh < H) ? 2 * oh : H - 1;  // 128 -> dummy
            xv1 = xr[r1 * 64 + lane]; nv1 = nr[r1 * 64 + lane];
            xv2 = xr[r2 * 64 + lane]; nv2 = nr[r2 * 64 + lane];
        }
        const bool rv0 = (oh > 0);                  // rows 2oh-2, 2oh-1 valid
        const bool rv2 = (oh < OH - 1);             // row 2oh valid
        const bool cOK = (lane < 63);               // col 2l+2 < 128

        // col-(2l+2) norms from lane l+1
        float nd0 = __shfl_down(nv0.x, 1);
        float nd1 = __shfl_down(nv1.x, 1);
        float nd2 = __shfl_down(nv2.x, 1);

        // masked window norms for set s = l+1 (k-order: row-major, kw 0..2)
        float n00 = rv0 ? nv0.x : 0.f, n01 = rv0 ? nv0.y : 0.f;
        float n02 = (rv0 && cOK) ? nd0 : 0.f;
        float n10 = rv0 ? nv1.x : 0.f, n11 = rv0 ? nv1.y : 0.f;
        float n12 = (rv0 && cOK) ? nd1 : 0.f;
        float n20 = rv2 ? nv2.x : 0.f, n21 = rv2 ? nv2.y : 0.f;
        float n22 = (rv2 && cOK) ? nd2 : 0.f;

        float m = 0.f;
        m = fmaxf(m, n00); m = fmaxf(m, n01); m = fmaxf(m, n02);
        m = fmaxf(m, n10); m = fmaxf(m, n11); m = fmaxf(m, n12);
        m = fmaxf(m, n20); m = fmaxf(m, n21); m = fmaxf(m, n22);

        float e00 = __expf(n00 - m), e01 = __expf(n01 - m), e02 = __expf(n02 - m);
        float e10 = __expf(n10 - m), e11 = __expf(n11 - m), e12 = __expf(n12 - m);
        float e20 = __expf(n20 - m), e21 = __expf(n21 - m), e22 = __expf(n22 - m);
        float denom = e00 + e01 + e02 + e10 + e11 + e12 + e20 + e21 + e22;
        float inv = 1.0f / denom;

        float w00 = rv0 ? e00 * inv : 0.f, w01 = rv0 ? e01 * inv : 0.f;
        float w02 = (rv0 && cOK) ? e02 * inv : 0.f;
        float w10 = rv0 ? e10 * inv : 0.f, w11 = rv0 ? e11 * inv : 0.f;
        float w12 = (rv0 && cOK) ? e12 * inv : 0.f;
        float w20 = rv2 ? e20 * inv : 0.f, w21 = rv2 ? e21 * inv : 0.f;
        float w22 = (rv2 && cOK) ? e22 * inv : 0.f;

        // col-(2l+2) x values from lane l+1
        float xd0 = __shfl_down(xv0.x, 1);
        float xd1 = __shfl_down(xv1.x, 1);
        float xd2 = __shfl_down(xv2.x, 1);

        float o = w00 * xv0.x + w01 * xv0.y + w02 * xd0
                + w10 * xv1.x + w11 * xv1.y + w12 * xd1
                + w20 * xv2.x + w21 * xv2.y + w22 * xd2;
        op[oh * OW + 1 + lane] = o;                 // out cols 1..64 (256B run)

        if (lane == 0) {
            // out[oh][0]: set[0] window cols {-2,-1,0}; only col 0 in-bounds.
            // col-0 norms are this lane's (masked) n00/n10/n20.
            float m0 = fmaxf(fmaxf(0.f, n00), fmaxf(n10, n20));
            float q0 = __expf(n00 - m0);
            float q1 = __expf(n10 - m0);
            float q2 = __expf(n20 - m0);
            float d0 = 6.f * __expf(0.f - m0) + q0 + q1 + q2;  // 6 OOB terms
            float i0 = 1.0f / d0;
            float t0 = rv0 ? q0 * i0 : 0.f;
            float t1 = rv0 ? q1 * i0 : 0.f;
            float t2 = rv2 ? q2 * i0 : 0.f;
            op[oh * OW] = t0 * xv0.x + t1 * xv1.x + t2 * xv2.x;
        }
    }
}

extern "C" void kernel_launch(void* const* d_in, const int* in_sizes, int n_in,
                              void* d_out, int out_size, void* d_ws, size_t ws_size,
                              hipStream_t stream) {
    const float* x = (const float*)d_in[0];
    float* out  = (float*)d_out;
    float* nbuf = (float*)d_ws;   // BATCH*H*W floats = 512 KB (only ws use)

    norm_kernel<<<512, 256, 0, stream>>>((const float4*)x, nbuf);
    // 8 images * 64 channel-groups = 512 blocks x 256 thr (wave = 1 channel)
    pool_kernel<<<512, 256, 0, stream>>>(x, nbuf, out);
}

// Round 12
// 224.135 us; speedup vs baseline: 1.0542x; 1.0542x over previous
//
#include <hip/hip_runtime.h>
#include <math.h>

#define BATCH 8
#define CH    256
#define H     128
#define W     128
#define HW    (H * W)          // 16384
#define OH    65
#define OW    65
#define NPIX  (OH * OW)        // 4225

// ---------------- K1: channel L2 norms, pure stream (verified) ----------------
// 512 blocks (2/CU) x 256 thr (4 waves). Block = 256-pixel tile of one image;
// wave wv covers channels [wv*64, wv*64+64). Per channel the wave reads
// 1 KB contiguous; 64 independent loads/lane -> deep pipeline. Primes L3 with x.
__global__ __launch_bounds__(256) void norm_kernel(const float4* __restrict__ x4,
                                                   float* __restrict__ nrm) {
    const int b    = blockIdx.x >> 6;      // 0..7
    const int t    = blockIdx.x & 63;      // 256-px tile within image
    const int lane = threadIdx.x & 63;
    const int wv   = threadIdx.x >> 6;     // 0..3

    const float4* p = x4 + (size_t)(b * CH + wv * 64) * (HW / 4) + t * 64 + lane;
    float4 a = {0.f, 0.f, 0.f, 0.f};
    #pragma unroll 8
    for (int c = 0; c < 64; ++c) {
        float4 v = p[(size_t)c * (HW / 4)];
        a.x += v.x * v.x; a.y += v.y * v.y;
        a.z += v.z * v.z; a.w += v.w * v.w;
    }
    __shared__ float part[4][256];
    ((float4*)part[wv])[lane] = a;         // flat px index = 4*lane+comp
    __syncthreads();
    float s = part[0][threadIdx.x] + part[1][threadIdx.x]
            + part[2][threadIdx.x] + part[3][threadIdx.x];
    nrm[(size_t)b * HW + t * 256 + threadIdx.x] = sqrtf(s);
}

// ---------------- K2: rolling-row pool, weights amortized over 4 channels ----
// 1024 blocks (4/CU) x 256 thr. Block = (b, 16-ch group g2, row-range q of 8);
// wave wv = 4 channels [g2*16+wv*4, +4), output rows [q*8, q*8+8(+1 for q=7)).
// Per oh: ONE in-lane softmax weight set (identical math to the R11-verified
// kernel) applied to 4 channel planes; x and norm rows roll in registers with
// 2 new sequential 512B row-loads per plane per step. Lane l owns cols
// (2l, 2l+1); it computes out[oh][l+1] fully (3rd col via shfl_down);
// lane 0 also writes out[oh][0] (set[0]: only col 0 in-bounds).
// OOB masking: nv=0 in denom (m seeded 0), weight=0 in numerator -- verified.
#define NQ 8
__global__ __launch_bounds__(256) void pool_kernel(const float* __restrict__ x,
                                                   const float* __restrict__ nrm,
                                                   float* __restrict__ out) {
    const int b    = blockIdx.x & 7;       // XCD pin: image -> XCD
    const int r    = blockIdx.x >> 3;      // 0..127
    const int g2   = r >> 3;               // 0..15 channel group-of-16
    const int q    = r & 7;                // 0..7 row range
    const int lane = threadIdx.x & 63;
    const int wv   = threadIdx.x >> 6;     // 0..3
    const int c0   = g2 * 16 + wv * 4;     // first of this wave's 4 channels
    const int oh0  = q * 8;
    const int ohN  = (q == NQ - 1) ? 9 : 8;

    const float2* xp = (const float2*)(x + (size_t)(b * CH + c0) * HW);
    const float2* nr = (const float2*)(nrm + (size_t)b * HW);
    float*       op0 = out + (size_t)(b * CH + c0) * NPIX;

    float2 a0[4], a1[4], a2[4];            // rolling x rows, 4 channels
    float2 n0, n1, n2;                     // rolling norm rows (shared)

    if (oh0 == 0) {
        n2 = nr[lane];  n0 = n2;  n1 = n2; // rows -2,-1: dummies, masked
        #pragma unroll
        for (int cc = 0; cc < 4; ++cc) {
            a2[cc] = xp[(size_t)cc * (HW / 2) + lane];
            a0[cc] = a2[cc];  a1[cc] = a2[cc];
        }
    } else {
        const int r0i = 2 * oh0 - 2, r1i = 2 * oh0 - 1, r2i = 2 * oh0;
        n0 = nr[r0i * 64 + lane];
        n1 = nr[r1i * 64 + lane];
        n2 = nr[r2i * 64 + lane];
        #pragma unroll
        for (int cc = 0; cc < 4; ++cc) {
            const size_t cb = (size_t)cc * (HW / 2);
            a0[cc] = xp[cb + r0i * 64 + lane];
            a1[cc] = xp[cb + r1i * 64 + lane];
            a2[cc] = xp[cb + r2i * 64 + lane];
        }
    }

    for (int i = 0; i < ohN; ++i) {
        const int oh = oh0 + i;
        if (i > 0) {
            const int r1i = 2 * oh - 1;                     // in [1,127]
            const int r2i = (2 * oh < H) ? 2 * oh : H - 1;  // 128 -> dummy
            n0 = n2;
            n1 = nr[r1i * 64 + lane];
            n2 = nr[r2i * 64 + lane];
            #pragma unroll
            for (int cc = 0; cc < 4; ++cc) {
                const size_t cb = (size_t)cc * (HW / 2);
                a0[cc] = a2[cc];
                a1[cc] = xp[cb + r1i * 64 + lane];
                a2[cc] = xp[cb + r2i * 64 + lane];
            }
        }
        const bool rv0 = (oh > 0);
        const bool rv2 = (oh < OH - 1);
        const bool cOK = (lane < 63);

        // ---- weight set for ow = lane+1 (verified R11 math) ----
        float nd0 = __shfl_down(n0.x, 1);
        float nd1 = __shfl_down(n1.x, 1);
        float nd2 = __shfl_down(n2.x, 1);

        float n00 = rv0 ? n0.x : 0.f, n01 = rv0 ? n0.y : 0.f;
        float n02 = (rv0 && cOK) ? nd0 : 0.f;
        float n10 = rv0 ? n1.x : 0.f, n11 = rv0 ? n1.y : 0.f;
        float n12 = (rv0 && cOK) ? nd1 : 0.f;
        float n20 = rv2 ? n2.x : 0.f, n21 = rv2 ? n2.y : 0.f;
        float n22 = (rv2 && cOK) ? nd2 : 0.f;

        float m = 0.f;
        m = fmaxf(m, n00); m = fmaxf(m, n01); m = fmaxf(m, n02);
        m = fmaxf(m, n10); m = fmaxf(m, n11); m = fmaxf(m, n12);
        m = fmaxf(m, n20); m = fmaxf(m, n21); m = fmaxf(m, n22);

        float e00 = __expf(n00 - m), e01 = __expf(n01 - m), e02 = __expf(n02 - m);
        float e10 = __expf(n10 - m), e11 = __expf(n11 - m), e12 = __expf(n12 - m);
        float e20 = __expf(n20 - m), e21 = __expf(n21 - m), e22 = __expf(n22 - m);
        float denom = e00 + e01 + e02 + e10 + e11 + e12 + e20 + e21 + e22;
        float inv = 1.0f / denom;

        float w00 = rv0 ? e00 * inv : 0.f, w01 = rv0 ? e01 * inv : 0.f;
        float w02 = (rv0 && cOK) ? e02 * inv : 0.f;
        float w10 = rv0 ? e10 * inv : 0.f, w11 = rv0 ? e11 * inv : 0.f;
        float w12 = (rv0 && cOK) ? e12 * inv : 0.f;
        float w20 = rv2 ? e20 * inv : 0.f, w21 = rv2 ? e21 * inv : 0.f;
        float w22 = (rv2 && cOK) ? e22 * inv : 0.f;

        // ---- ow = 0 weights (set[0]: cols {-2,-1,0}; shared across channels) ----
        float m0 = fmaxf(fmaxf(0.f, n00), fmaxf(n10, n20));
        float p0 = __expf(n00 - m0);
        float p1 = __expf(n10 - m0);
        float p2 = __expf(n20 - m0);
        float d0 = 6.f * __expf(0.f - m0) + p0 + p1 + p2;   // 6 OOB + 3 col-0
        float i0 = 1.0f / d0;
        float t0 = rv0 ? p0 * i0 : 0.f;
        float t1 = rv0 ? p1 * i0 : 0.f;
        float t2 = rv2 ? p2 * i0 : 0.f;

        // ---- apply to the 4 channel planes ----
        #pragma unroll
        for (int cc = 0; cc < 4; ++cc) {
            float xd0 = __shfl_down(a0[cc].x, 1);
            float xd1 = __shfl_down(a1[cc].x, 1);
            float xd2 = __shfl_down(a2[cc].x, 1);
            float o = w00 * a0[cc].x + w01 * a0[cc].y + w02 * xd0
                    + w10 * a1[cc].x + w11 * a1[cc].y + w12 * xd1
                    + w20 * a2[cc].x + w21 * a2[cc].y + w22 * xd2;
            float* op = op0 + (size_t)cc * NPIX;
            op[oh * OW + 1 + lane] = o;                     // ow 1..64, 256B run
            if (lane == 0)
                op[oh * OW] = t0 * a0[cc].x + t1 * a1[cc].x + t2 * a2[cc].x;
        }
    }
}

extern "C" void kernel_launch(void* const* d_in, const int* in_sizes, int n_in,
                              void* d_out, int out_size, void* d_ws, size_t ws_size,
                              hipStream_t stream) {
    const float* x = (const float*)d_in[0];
    float* out  = (float*)d_out;
    float* nbuf = (float*)d_ws;   // BATCH*H*W floats = 512 KB (only ws use)

    norm_kernel<<<512, 256, 0, stream>>>((const float4*)x, nbuf);
    // 8 images * 16 ch-groups * 8 row-ranges = 1024 blocks x 256 thr
    pool_kernel<<<1024, 256, 0, stream>>>(x, nbuf, out);
}